// Round 1
// baseline (838.258 us; speedup 1.0000x reference)
//
#include <hip/hip_runtime.h>
#include <math.h>

namespace {
constexpr int H    = 4096;   // hidden size
constexpr int E    = 256;    // experts
constexpr int TOPK = 8;
constexpr int BM   = 32;     // tokens per block
constexpr int BK   = 32;     // k-chunk
constexpr int XS_LD = BM + 4;  // 36 (row stride of xT tile, float4-aligned: 144 B)
constexpr int WS_LD = E + 4;   // 260 (row stride of wT tile, float4-aligned: 1040 B)
constexpr int LDS_FLOATS = BK * XS_LD + BK * WS_LD;  // 1152 + 8320 = 9472 (37 KB)
}

// One block: 32 tokens x all 256 experts. Thread (tx,ty): tx in [0,32) -> 8 experts,
// ty in [0,8) -> 4 tokens. acc[4][8] per thread. After GEMM, scores go to LDS and
// each wave does softmax + top-8 for 8 tokens via 64-lane butterflies.
__global__ __launch_bounds__(256, 2)
void moe_gate_kernel(const float* __restrict__ X, const float* __restrict__ W,
                     float* __restrict__ out_idx, float* __restrict__ out_w) {
    __shared__ float lds[LDS_FLOATS];
    float* xs = lds;                  // [BK][XS_LD]  (k-major: xs[k][m])
    float* ws = lds + BK * XS_LD;     // [BK][WS_LD]  (k-major: ws[k][e])

    const int tid = threadIdx.x;
    const int tx  = tid & 31;
    const int ty  = tid >> 5;
    const int m0  = blockIdx.x * BM;

    float acc[4][8];
    #pragma unroll
    for (int i = 0; i < 4; ++i) {
        #pragma unroll
        for (int j = 0; j < 8; ++j) acc[i][j] = 0.0f;
    }

    // global-load assignment: thread loads x row lr, cols [lc,lc+4); w rows lr+32i
    const int lr = tid >> 3;          // 0..31
    const int lc = (tid & 7) * 4;     // 0,4,..,28
    const float* xg = X + (size_t)(m0 + lr) * H + lc;
    const float* wg = W + (size_t)lr * H + lc;

    for (int kc = 0; kc < H; kc += BK) {
        float4 xv = *(const float4*)(xg + kc);
        float4 wv[8];
        #pragma unroll
        for (int i = 0; i < 8; ++i) {
            wv[i] = *(const float4*)(wg + (size_t)i * 32 * H + kc);
        }

        __syncthreads();  // previous iter's LDS reads done
        #pragma unroll
        for (int j = 0; j < 4; ++j) {
            xs[(lc + j) * XS_LD + lr] = ((const float*)&xv)[j];
        }
        #pragma unroll
        for (int i = 0; i < 8; ++i) {
            #pragma unroll
            for (int j = 0; j < 4; ++j) {
                ws[(lc + j) * WS_LD + i * 32 + lr] = ((const float*)&wv[i])[j];
            }
        }
        __syncthreads();

        #pragma unroll
        for (int kk = 0; kk < BK; ++kk) {
            float4 xa  = *(const float4*)(xs + kk * XS_LD + ty * 4);
            float4 wb0 = *(const float4*)(ws + kk * WS_LD + tx * 8);
            float4 wb1 = *(const float4*)(ws + kk * WS_LD + tx * 8 + 4);
            const float xr[4] = {xa.x, xa.y, xa.z, xa.w};
            const float wr[8] = {wb0.x, wb0.y, wb0.z, wb0.w,
                                 wb1.x, wb1.y, wb1.z, wb1.w};
            #pragma unroll
            for (int i = 0; i < 4; ++i) {
                #pragma unroll
                for (int j = 0; j < 8; ++j) {
                    acc[i][j] = fmaf(xr[i], wr[j], acc[i][j]);
                }
            }
        }
    }

    // scores -> LDS (reuse the tile buffer): sc[token][expert], row stride WS_LD
    __syncthreads();
    float* sc = lds;
    #pragma unroll
    for (int i = 0; i < 4; ++i) {
        *(float4*)(sc + (ty * 4 + i) * WS_LD + tx * 8) =
            make_float4(acc[i][0], acc[i][1], acc[i][2], acc[i][3]);
        *(float4*)(sc + (ty * 4 + i) * WS_LD + tx * 8 + 4) =
            make_float4(acc[i][4], acc[i][5], acc[i][6], acc[i][7]);
    }
    __syncthreads();

    const int wave = tid >> 6;   // 0..3
    const int lane = tid & 63;

    for (int t8 = 0; t8 < 8; ++t8) {
        const int t = wave * 8 + t8;
        float4 pv = *(const float4*)(sc + t * WS_LD + lane * 4);
        float v0 = pv.x, v1 = pv.y, v2 = pv.z, v3 = pv.w;

        // max over 256
        float M = fmaxf(fmaxf(v0, v1), fmaxf(v2, v3));
        #pragma unroll
        for (int off = 32; off > 0; off >>= 1) {
            M = fmaxf(M, __shfl_xor(M, off, 64));
        }
        // softmax probs (full denominator, mirroring reference)
        float p0 = expf(v0 - M), p1 = expf(v1 - M), p2 = expf(v2 - M), p3 = expf(v3 - M);
        float z = p0 + p1 + p2 + p3;
        #pragma unroll
        for (int off = 32; off > 0; off >>= 1) {
            z += __shfl_xor(z, off, 64);
        }
        p0 /= z; p1 /= z; p2 /= z; p3 /= z;

        // top-8 with lower-index tie-break (matches lax.top_k)
        float tv[TOPK]; int ti[TOPK];
        #pragma unroll
        for (int s = 0; s < TOPK; ++s) {
            float bv = p0; int bi = lane * 4;
            if (p1 > bv || (p1 == bv && lane * 4 + 1 < bi)) { bv = p1; bi = lane * 4 + 1; }
            if (p2 > bv || (p2 == bv && lane * 4 + 2 < bi)) { bv = p2; bi = lane * 4 + 2; }
            if (p3 > bv || (p3 == bv && lane * 4 + 3 < bi)) { bv = p3; bi = lane * 4 + 3; }
            #pragma unroll
            for (int off = 32; off > 0; off >>= 1) {
                float ov = __shfl_xor(bv, off, 64);
                int   oi = __shfl_xor(bi, off, 64);
                if (ov > bv || (ov == bv && oi < bi)) { bv = ov; bi = oi; }
            }
            tv[s] = bv; ti[s] = bi;
            if ((bi >> 2) == lane) {
                const int sl = bi & 3;
                if      (sl == 0) p0 = -1.0f;
                else if (sl == 1) p1 = -1.0f;
                else if (sl == 2) p2 = -1.0f;
                else              p3 = -1.0f;
            }
        }

        if (lane == 0) {
            float den = tv[0] + tv[1] + tv[2] + tv[3] + tv[4] + tv[5] + tv[6] + tv[7] + 1e-20f;
            float scl = 2.5f / den;
            size_t tok = (size_t)(m0 + t);
            #pragma unroll
            for (int s = 0; s < TOPK; ++s) {
                out_idx[tok * TOPK + s] = (float)ti[s];
                out_w[tok * TOPK + s]   = tv[s] * scl;
            }
        }
    }
}

extern "C" void kernel_launch(void* const* d_in, const int* in_sizes, int n_in,
                              void* d_out, int out_size, void* d_ws, size_t ws_size,
                              hipStream_t stream) {
    const float* X = (const float*)d_in[0];   // [T, H] fp32 (4*4096 x 4096)
    const float* W = (const float*)d_in[1];   // [E, H] fp32
    float* out = (float*)d_out;
    const int T = in_sizes[0] / H;            // 16384
    float* out_idx = out;                     // T*8 indices (as float values)
    float* out_w   = out + (size_t)T * TOPK;  // T*8 weights

    dim3 grid(T / BM), block(256);
    hipLaunchKernelGGL(moe_gate_kernel, grid, block, 0, stream,
                       X, W, out_idx, out_w);
}

// Round 3
// 686.380 us; speedup vs baseline: 1.2213x; 1.2213x over previous
//
#include <hip/hip_runtime.h>
#include <math.h>

typedef _Float16 half8  __attribute__((ext_vector_type(8)));
typedef _Float16 half4v __attribute__((ext_vector_type(4)));
typedef float    f32x16 __attribute__((ext_vector_type(16)));

namespace {
constexpr int H      = 4096;
constexpr int E      = 256;
constexpr int TOPK   = 8;
constexpr int NCAND  = 12;           // screened candidates per token
constexpr int BM     = 64;           // tokens per block (main kernel)
constexpr int BK     = 32;           // k per chunk
constexpr int NCHUNK = H / BK;       // 128
constexpr int SLD    = E + 4;        // 260, score row stride (floats)
constexpr float DELTA = 5e-4f;       // near-tie rescue threshold (logit units)
constexpr size_t WF_BYTES = (size_t)E * H * 2 * 2;  // 4 MB: hi+lo fp16
constexpr int SMEM_BYTES = BM * SLD * 4;  // 66560 (A dbuf = 16 KB fits inside)
}

// ---------------- W pre-convert: fp32 -> fragment-ordered hi/lo fp16 --------
// Layout (halves): [nt(8)][ks(256)][hilo(2)][lane(64)][j(8)]
//   element W[e][k] (scaled by 64): nt=e>>5, ks=k>>4,
//   lane=(e&31) | (((k>>3)&1)<<5), j=k&7
__global__ void convert_w_kernel(const float* __restrict__ W,
                                 _Float16* __restrict__ Wf) {
    int t  = blockIdx.x * blockDim.x + threadIdx.x;
    int e  = t >> 10;
    int kq = t & 1023;           // k = kq*4
    float4 w4 = *(const float4*)(W + ((size_t)e << 12) + (kq << 2));
    float x0 = w4.x * 64.0f, x1 = w4.y * 64.0f, x2 = w4.z * 64.0f, x3 = w4.w * 64.0f;
    _Float16 h0 = (_Float16)x0, h1 = (_Float16)x1, h2 = (_Float16)x2, h3 = (_Float16)x3;
    _Float16 l0 = (_Float16)(x0 - (float)h0), l1 = (_Float16)(x1 - (float)h1);
    _Float16 l2 = (_Float16)(x2 - (float)h2), l3 = (_Float16)(x3 - (float)h3);
    int k    = kq << 2;
    int nt   = e >> 5;
    int ks   = k >> 4;
    int lane = (e & 31) | (((k >> 3) & 1) << 5);
    int j    = k & 7;            // 0 or 4
    size_t base = (((size_t)nt * 256 + ks) * 2) * 512 + lane * 8 + j;
    half4v hv = {h0, h1, h2, h3};
    half4v lv = {l0, l1, l2, l3};
    *(half4v*)(Wf + base)       = hv;   // hilo=0
    *(half4v*)(Wf + base + 512) = lv;   // hilo=1
}

// ---------------- main fused kernel: split-fp16 MFMA GEMM + top8 ------------
struct BF { half8 h[2][2]; half8 l[2][2]; };  // [k_step][n_tile]

__global__ __launch_bounds__(512, 2)
void moe_gate_mfma(const float* __restrict__ X, const _Float16* __restrict__ Wf,
                   const float* __restrict__ Wg,
                   float* __restrict__ out_idx, float* __restrict__ out_w) {
    __shared__ __align__(16) char smem[SMEM_BYTES];
    _Float16* Abuf = (_Float16*)smem;       // 2 buffers x 4096 halves
    float*    sc   = (float*)smem;          // epilogue scores [64][SLD]

    const int tid  = threadIdx.x;
    const int lane = tid & 63;
    const int wave = tid >> 6;      // 0..7
    const int wr   = wave >> 2;     // m half (0..1)
    const int wc   = wave & 3;      // n quarter (0..3), 64 experts each
    const int m0   = blockIdx.x * BM;

    // staging: thread -> (m_s, k = kq_s*4) of the 64x32 fp32 X tile
    const int m_s  = tid >> 3;      // 0..63
    const int kq_s = tid & 7;       // 0..7
    const int ks_s = kq_s >> 2;                              // k_step 0/1
    const int mt_s = m_s >> 5;                               // m tile 0/1
    const int ln_s = (m_s & 31) | (((kq_s >> 1) & 1) << 5);  // frag lane
    const int j_s  = (kq_s & 1) * 4;                         // frag elem 0/4
    const int dst_s = ((ks_s * 2 + mt_s) * 2) * 512 + ln_s * 8 + j_s;
    const float* xgp = X + (size_t)(m0 + m_s) * H + kq_s * 4;

    f32x16 acc[2];
    #pragma unroll
    for (int nt = 0; nt < 2; ++nt)
        #pragma unroll
        for (int r = 0; r < 16; ++r) acc[nt][r] = 0.0f;

    auto load_b = [&](int kc, BF& b) {
        #pragma unroll
        for (int ks = 0; ks < 2; ++ks)
            #pragma unroll
            for (int nt = 0; nt < 2; ++nt) {
                size_t base = (((size_t)(2 * wc + nt) * 256 + (kc * 2 + ks)) * 2) * 512
                              + lane * 8;
                b.h[ks][nt] = *(const half8*)(Wf + base);
                b.l[ks][nt] = *(const half8*)(Wf + base + 512);
            }
    };
    auto stage = [&](int bufIdx, float4 xv) {
        _Float16* buf = Abuf + bufIdx * 4096;
        float x0 = xv.x, x1 = xv.y, x2 = xv.z, x3 = xv.w;
        _Float16 h0 = (_Float16)x0, h1 = (_Float16)x1, h2 = (_Float16)x2, h3 = (_Float16)x3;
        _Float16 l0 = (_Float16)(x0 - (float)h0), l1 = (_Float16)(x1 - (float)h1);
        _Float16 l2 = (_Float16)(x2 - (float)h2), l3 = (_Float16)(x3 - (float)h3);
        half4v hv = {h0, h1, h2, h3};
        half4v lv = {l0, l1, l2, l3};
        *(half4v*)(buf + dst_s)       = hv;
        *(half4v*)(buf + dst_s + 512) = lv;
    };
    auto compute = [&](int bufIdx, const BF& b) {
        const _Float16* buf = Abuf + bufIdx * 4096;
        #pragma unroll
        for (int ks = 0; ks < 2; ++ks) {
            const _Float16* p = buf + (ks * 2 + wr) * 1024 + lane * 8;
            half8 a_hi = *(const half8*)p;
            half8 a_lo = *(const half8*)(p + 512);
            #pragma unroll
            for (int nt = 0; nt < 2; ++nt) {
                acc[nt] = __builtin_amdgcn_mfma_f32_32x32x16_f16(a_hi, b.h[ks][nt], acc[nt], 0, 0, 0);
                acc[nt] = __builtin_amdgcn_mfma_f32_32x32x16_f16(a_lo, b.h[ks][nt], acc[nt], 0, 0, 0);
                acc[nt] = __builtin_amdgcn_mfma_f32_32x32x16_f16(a_hi, b.l[ks][nt], acc[nt], 0, 0, 0);
            }
        }
    };

    // prologue
    BF bcur;
    load_b(0, bcur);
    float4 xv = *(const float4*)(xgp);
    stage(0, xv);
    __syncthreads();
    float4 xnxt = *(const float4*)(xgp + BK);

    for (int kc = 0; kc < NCHUNK; ++kc) {
        BF bnxt;
        float4 xfar = make_float4(0.f, 0.f, 0.f, 0.f);
        if (kc + 1 < NCHUNK) load_b(kc + 1, bnxt);
        if (kc + 2 < NCHUNK) xfar = *(const float4*)(xgp + (size_t)(kc + 2) * BK);
        compute(kc & 1, bcur);
        if (kc + 1 < NCHUNK) {
            stage((kc + 1) & 1, xnxt);
            __syncthreads();
        }
        bcur = bnxt;
        xnxt = xfar;
    }

    // -------- logits -> LDS (undo the x64 W prescale) --------
    __syncthreads();
    #pragma unroll
    for (int nt = 0; nt < 2; ++nt) {
        #pragma unroll
        for (int r = 0; r < 16; ++r) {
            int row = (r & 3) + 8 * (r >> 2) + 4 * (lane >> 5);
            int col = lane & 31;
            sc[(wr * 32 + row) * SLD + wc * 64 + nt * 32 + col] = acc[nt][r] * 0.015625f;
        }
    }
    __syncthreads();

    // -------- top-12 screen on logits + fp64 rescue for near-ties -----------
    for (int t8 = 0; t8 < 8; ++t8) {
        const int t = wave * 8 + t8;
        float4 pv = *(const float4*)(sc + t * SLD + lane * 4);
        float p0 = pv.x, p1 = pv.y, p2 = pv.z, p3 = pv.w;

        float tv[NCAND]; int ti[NCAND];
        #pragma unroll
        for (int s = 0; s < NCAND; ++s) {
            float bv = p0; int bi = lane * 4;
            if (p1 > bv || (p1 == bv && lane * 4 + 1 < bi)) { bv = p1; bi = lane * 4 + 1; }
            if (p2 > bv || (p2 == bv && lane * 4 + 2 < bi)) { bv = p2; bi = lane * 4 + 2; }
            if (p3 > bv || (p3 == bv && lane * 4 + 3 < bi)) { bv = p3; bi = lane * 4 + 3; }
            #pragma unroll
            for (int off = 32; off > 0; off >>= 1) {
                float ov = __shfl_xor(bv, off, 64);
                int   oi = __shfl_xor(bi, off, 64);
                if (ov > bv || (ov == bv && oi < bi)) { bv = ov; bi = oi; }
            }
            tv[s] = bv; ti[s] = bi;
            if ((bi >> 2) == lane) {
                const int sl = bi & 3;
                if      (sl == 0) p0 = -3e38f;
                else if (sl == 1) p1 = -3e38f;
                else if (sl == 2) p2 = -3e38f;
                else              p3 = -3e38f;
            }
        }

        // near-tie detection among the decisive gaps (ranks 0-1 .. 8-9)
        bool rescue = false;
        #pragma unroll
        for (int g = 0; g < 9; ++g) rescue |= (tv[g] - tv[g + 1] < DELTA);

        if (rescue) {  // wave-uniform branch (tv identical across lanes)
            double dv[NCAND];
            const float* xr = X + (size_t)(m0 + t) * H;
            #pragma unroll 1
            for (int c = 0; c < NCAND; ++c) {
                const float* wrow = Wg + (size_t)ti[c] * H;
                double s_ = 0.0;
                #pragma unroll
                for (int it = 0; it < 16; ++it) {
                    float4 xa = *(const float4*)(xr + it * 256 + lane * 4);
                    float4 wa = *(const float4*)(wrow + it * 256 + lane * 4);
                    s_ += (double)xa.x * wa.x + (double)xa.y * wa.y
                        + (double)xa.z * wa.z + (double)xa.w * wa.w;
                }
                #pragma unroll
                for (int off = 32; off > 0; off >>= 1) s_ += __shfl_xor(s_, off, 64);
                dv[c] = s_;
            }
            // exact selection sort of top 8 (desc, lower index on tie)
            int si[NCAND];
            #pragma unroll
            for (int c = 0; c < NCAND; ++c) si[c] = ti[c];
            #pragma unroll
            for (int a = 0; a < TOPK; ++a) {
                int best = a;
                #pragma unroll
                for (int b = a + 1; b < NCAND; ++b) {
                    if (dv[b] > dv[best] || (dv[b] == dv[best] && si[b] < si[best])) best = b;
                }
                double tdv = dv[a]; dv[a] = dv[best]; dv[best] = tdv;
                int    tsi = si[a]; si[a] = si[best]; si[best] = tsi;
            }
            #pragma unroll
            for (int s = 0; s < TOPK; ++s) { tv[s] = (float)dv[s]; ti[s] = si[s]; }
        }

        if (lane == 0) {
            // weights = 2.5 * softmax over the top-8 logits (full-Z cancels)
            float M = tv[0];
            float e8[TOPK]; float den = 0.0f;
            #pragma unroll
            for (int s = 0; s < TOPK; ++s) { e8[s] = expf(tv[s] - M); den += e8[s]; }
            float scl = 2.5f / den;
            size_t tok = (size_t)(m0 + t);
            #pragma unroll
            for (int s = 0; s < TOPK; ++s) {
                out_idx[tok * TOPK + s] = (float)ti[s];
                out_w[tok * TOPK + s]   = e8[s] * scl;
            }
        }
    }
}

// ---------------- fallback (round-1 fp32 kernel, correctness-proven) --------
namespace fb {
constexpr int BM = 32, BK = 32;
constexpr int XS_LD = BM + 4, WS_LD = E + 4;
constexpr int LDS_FLOATS = BK * XS_LD + BK * WS_LD;
}

__global__ __launch_bounds__(256, 2)
void moe_gate_fallback(const float* __restrict__ X, const float* __restrict__ W,
                       float* __restrict__ out_idx, float* __restrict__ out_w) {
    __shared__ float lds[fb::LDS_FLOATS];
    float* xs = lds;
    float* ws = lds + fb::BK * fb::XS_LD;
    const int tid = threadIdx.x;
    const int tx = tid & 31, ty = tid >> 5;
    const int m0 = blockIdx.x * fb::BM;
    float acc[4][8];
    #pragma unroll
    for (int i = 0; i < 4; ++i)
        #pragma unroll
        for (int j = 0; j < 8; ++j) acc[i][j] = 0.0f;
    const int lr = tid >> 3, lc = (tid & 7) * 4;
    const float* xg = X + (size_t)(m0 + lr) * H + lc;
    const float* wg = W + (size_t)lr * H + lc;
    for (int kc = 0; kc < H; kc += fb::BK) {
        float4 xv = *(const float4*)(xg + kc);
        float4 wv[8];
        #pragma unroll
        for (int i = 0; i < 8; ++i) wv[i] = *(const float4*)(wg + (size_t)i * 32 * H + kc);
        __syncthreads();
        #pragma unroll
        for (int j = 0; j < 4; ++j) xs[(lc + j) * fb::XS_LD + lr] = ((const float*)&xv)[j];
        #pragma unroll
        for (int i = 0; i < 8; ++i)
            #pragma unroll
            for (int j = 0; j < 4; ++j)
                ws[(lc + j) * fb::WS_LD + i * 32 + lr] = ((const float*)&wv[i])[j];
        __syncthreads();
        #pragma unroll
        for (int kk = 0; kk < fb::BK; ++kk) {
            float4 xa = *(const float4*)(xs + kk * fb::XS_LD + ty * 4);
            float4 wb0 = *(const float4*)(ws + kk * fb::WS_LD + tx * 8);
            float4 wb1 = *(const float4*)(ws + kk * fb::WS_LD + tx * 8 + 4);
            const float xr[4] = {xa.x, xa.y, xa.z, xa.w};
            const float wr8[8] = {wb0.x, wb0.y, wb0.z, wb0.w, wb1.x, wb1.y, wb1.z, wb1.w};
            #pragma unroll
            for (int i = 0; i < 4; ++i)
                #pragma unroll
                for (int j = 0; j < 8; ++j) acc[i][j] = fmaf(xr[i], wr8[j], acc[i][j]);
        }
    }
    __syncthreads();
    float* sc = lds;
    #pragma unroll
    for (int i = 0; i < 4; ++i) {
        *(float4*)(sc + (ty * 4 + i) * fb::WS_LD + tx * 8) =
            make_float4(acc[i][0], acc[i][1], acc[i][2], acc[i][3]);
        *(float4*)(sc + (ty * 4 + i) * fb::WS_LD + tx * 8 + 4) =
            make_float4(acc[i][4], acc[i][5], acc[i][6], acc[i][7]);
    }
    __syncthreads();
    const int wave = tid >> 6, lane = tid & 63;
    for (int t8 = 0; t8 < 8; ++t8) {
        const int t = wave * 8 + t8;
        float4 pv = *(const float4*)(sc + t * fb::WS_LD + lane * 4);
        float v0 = pv.x, v1 = pv.y, v2 = pv.z, v3 = pv.w;
        float M = fmaxf(fmaxf(v0, v1), fmaxf(v2, v3));
        #pragma unroll
        for (int off = 32; off > 0; off >>= 1) M = fmaxf(M, __shfl_xor(M, off, 64));
        float p0 = expf(v0 - M), p1 = expf(v1 - M), p2 = expf(v2 - M), p3 = expf(v3 - M);
        float z = p0 + p1 + p2 + p3;
        #pragma unroll
        for (int off = 32; off > 0; off >>= 1) z += __shfl_xor(z, off, 64);
        p0 /= z; p1 /= z; p2 /= z; p3 /= z;
        float tv[TOPK]; int ti[TOPK];
        #pragma unroll
        for (int s = 0; s < TOPK; ++s) {
            float bv = p0; int bi = lane * 4;
            if (p1 > bv || (p1 == bv && lane * 4 + 1 < bi)) { bv = p1; bi = lane * 4 + 1; }
            if (p2 > bv || (p2 == bv && lane * 4 + 2 < bi)) { bv = p2; bi = lane * 4 + 2; }
            if (p3 > bv || (p3 == bv && lane * 4 + 3 < bi)) { bv = p3; bi = lane * 4 + 3; }
            #pragma unroll
            for (int off = 32; off > 0; off >>= 1) {
                float ov = __shfl_xor(bv, off, 64);
                int   oi = __shfl_xor(bi, off, 64);
                if (ov > bv || (ov == bv && oi < bi)) { bv = ov; bi = oi; }
            }
            tv[s] = bv; ti[s] = bi;
            if ((bi >> 2) == lane) {
                const int sl = bi & 3;
                if      (sl == 0) p0 = -1.0f;
                else if (sl == 1) p1 = -1.0f;
                else if (sl == 2) p2 = -1.0f;
                else              p3 = -1.0f;
            }
        }
        if (lane == 0) {
            float den = tv[0] + tv[1] + tv[2] + tv[3] + tv[4] + tv[5] + tv[6] + tv[7] + 1e-20f;
            float scl = 2.5f / den;
            size_t tok = (size_t)(m0 + t);
            #pragma unroll
            for (int s = 0; s < TOPK; ++s) {
                out_idx[tok * TOPK + s] = (float)ti[s];
                out_w[tok * TOPK + s]   = tv[s] * scl;
            }
        }
    }
}

extern "C" void kernel_launch(void* const* d_in, const int* in_sizes, int n_in,
                              void* d_out, int out_size, void* d_ws, size_t ws_size,
                              hipStream_t stream) {
    const float* X = (const float*)d_in[0];
    const float* W = (const float*)d_in[1];
    float* out = (float*)d_out;
    const int T = in_sizes[0] / H;
    float* out_idx = out;
    float* out_w   = out + (size_t)T * TOPK;

    if (ws_size >= WF_BYTES && (T % BM) == 0) {
        _Float16* Wf = (_Float16*)d_ws;
        hipLaunchKernelGGL(convert_w_kernel, dim3((E * (H / 4)) / 256), dim3(256), 0, stream, W, Wf);
        hipLaunchKernelGGL(moe_gate_mfma, dim3(T / BM), dim3(512), 0, stream, X, Wf, W, out_idx, out_w);
    } else {
        hipLaunchKernelGGL(moe_gate_fallback, dim3(T / fb::BM), dim3(256), 0, stream, X, W, out_idx, out_w);
    }
}